// Round 7
// baseline (3280.233 us; speedup 1.0000x reference)
//
#include <hip/hip_runtime.h>
#include <cstdint>
#include <cstddef>

// ---------------------------------------------------------------------------
// BsPINN forward, int8 dual-fixed-point MFMA (round 7).
// R6 post-mortem: i8 kernel was latency-bound (VGPR 156 -> occ 11%, MfmaUtil
// 18%) + A re-fetched 4x (n-outer grid). R7: global_load_lds DMA staging
// (no staging VGPRs), __launch_bounds__(256,4) (cap 128 VGPR), grid n-fast.
// Scheme (proven R6, absmax 4.9e-4):
//   h = H1*2^-6 + H2*2^-13 (i8 pair), w = W1*2^-10 + W2*2^-17 (i8 pair)
//   preact = (sum H1W1)*2^-16 + (sum H1W2 + H2W1)*2^-23 + bias
//   3 x mfma_i32_16x16x64_i8 per K=64; i32 accum exact (<8M << 2^31).
// ---------------------------------------------------------------------------

typedef int          intx4   __attribute__((ext_vector_type(4)));
typedef float        floatx8 __attribute__((ext_vector_type(8)));
typedef signed char  i8x8    __attribute__((ext_vector_type(8)));

__device__ __forceinline__ float tanh_fast(float x) {
    float e = __expf(2.0f * x);
    return 1.0f - 2.0f / (e + 1.0f);
}
// h in (-1,1) -> H1 = rne(h*64), H2 = rne((h-H1/64)*8192); both in [-64,64].
__device__ __forceinline__ void quant_h(float o, signed char& q1, signed char& q2) {
    float a = rintf(o * 64.0f);
    float r = fmaf(a, -0.015625f, o);          // o - a/64, exact
    q1 = (signed char)(int)a;
    q2 = (signed char)(int)rintf(r * 8192.0f);
}
// |w|<=0.0542 -> W1 = rne(w*1024) in [-56,56], W2 = rne((w-W1/1024)*2^17).
__device__ __forceinline__ void quant_w(float v, signed char& q1, signed char& q2) {
    float a = rintf(v * 1024.0f);
    float r = fmaf(a, -0.0009765625f, v);      // v - a/1024, exact
    q1 = (signed char)(int)a;
    q2 = (signed char)(int)rintf(r * 131072.0f);
}
// async global->LDS, 16B per lane; LDS dest = wave-uniform base + lane*16.
__device__ __forceinline__ void async16(const void* g, void* l) {
    __builtin_amdgcn_global_load_lds(
        (const __attribute__((address_space(1))) void*)g,
        (__attribute__((address_space(3))) void*)l,
        16, 0, 0);
}

// ---------------------------------------------------------------------------
// Weight transpose + int8 hi/lo quant: fp32 W[K][N] -> i8 W1q/W2q[N][K].
// ---------------------------------------------------------------------------
__global__ __launch_bounds__(256)
void transposeQ(const float* __restrict__ W,
                signed char* __restrict__ W1q, signed char* __restrict__ W2q) {
    __shared__ float tile[32][33];
    const int tx = threadIdx.x & 31;
    const int ty = threadIdx.x >> 5;     // 0..7
    #pragma unroll
    for (int j = 0; j < 4; ++j) {
        int r = ty + j * 8;
        tile[r][tx] = W[(size_t)(blockIdx.y * 32 + r) * 1024 + blockIdx.x * 32 + tx];
    }
    __syncthreads();
    #pragma unroll
    for (int j = 0; j < 4; ++j) {
        int r = ty + j * 8;
        float v = tile[tx][r];
        signed char q1, q2;
        quant_w(v, q1, q2);
        const size_t o = (size_t)(blockIdx.x * 32 + r) * 1024 + blockIdx.y * 32 + tx;
        W1q[o] = q1;
        W2q[o] = q2;
    }
}

// ---------------------------------------------------------------------------
// Layer 0 (fp32 in): h0 = tanh(xa*W0[0][:] + xb*W0[1][:] + b0) -> i8 pair.
// ---------------------------------------------------------------------------
__global__ __launch_bounds__(256)
void layer0_kernel(const float* __restrict__ X, const float* __restrict__ W0,
                   const float* __restrict__ b0,
                   signed char* __restrict__ H1, signed char* __restrict__ H2) {
    const int idx = blockIdx.x * 256 + threadIdx.x;
    const int row = idx >> 7;
    const int j0  = (idx & 127) << 3;
    const float x0 = X[row * 2 + 0];
    const float x1 = X[row * 2 + 1];
    const float xa = x0 * 0.31830988618379067f - 1.0f;   // x0/pi - 1
    const float xb = 2.0f * x1 - 1.0f;
    floatx8 wa = *(const floatx8*)(W0 + j0);
    floatx8 wb = *(const floatx8*)(W0 + 1024 + j0);
    floatx8 bb = *(const floatx8*)(b0 + j0);
    i8x8 o1, o2;
    #pragma unroll
    for (int j = 0; j < 8; ++j) {
        float v = fmaf(xa, wa[j], fmaf(xb, wb[j], bb[j]));
        float o = tanh_fast(v);
        signed char q1, q2;
        quant_h(o, q1, q2);
        o1[j] = q1;
        o2[j] = q2;
    }
    const size_t off = (size_t)row * 1024 + j0;
    *(i8x8*)(H1 + off) = o1;
    *(i8x8*)(H2 + off) = o2;
}

// ---------------------------------------------------------------------------
// GEMM + bias + tanh, i8 dual-fixed-point, DMA-staged.
// Grid: (n-blocks=8, m-blocks) -> n fast: the 8 blocks sharing one A-tile
// run concurrently (A fetched once). 128x128 tile, BK=64, 4 waves (2x2),
// 4x4 16x16x64 frags. 3 MFMAs/frag/kiter.
// ---------------------------------------------------------------------------
__global__ __launch_bounds__(256, 4)
void gemm_tanh_i8(const signed char* __restrict__ A1, const signed char* __restrict__ A2,
                  const signed char* __restrict__ B1, const signed char* __restrict__ B2,
                  const float* __restrict__ bias,
                  signed char* __restrict__ C1, signed char* __restrict__ C2, int KB) {
    __shared__ signed char As1[128 * 64];
    __shared__ signed char As2[128 * 64];
    __shared__ signed char Bs1[128 * 64];
    __shared__ signed char Bs2[128 * 64];

    const int tid  = threadIdx.x;
    const int lane = tid & 63;
    const int wave = tid >> 6;
    const int n0 = blockIdx.x * 128;          // n fast (8 blocks share A)
    const int m0 = blockIdx.y * 128;
    const int kbeg   = (n0 / KB) * KB;
    const int kiters = KB >> 6;
    const int wm = (wave & 1) << 6;
    const int wn = (wave >> 1) << 6;
    const int r = lane & 15;
    const int q = lane >> 4;

    intx4 accM[4][4], accX[4][4];
    #pragma unroll
    for (int i = 0; i < 4; ++i)
        #pragma unroll
        for (int j = 0; j < 4; ++j) {
            accM[i][j] = intx4{0, 0, 0, 0};
            accX[i][j] = intx4{0, 0, 0, 0};
        }

    for (int t = 0; t < kiters; ++t) {
        const int k = kbeg + (t << 6);
        if (t) __syncthreads();               // prior iter's ds_reads done
        // DMA-stage 4 tiles (128x64 i8 = 8 KB each): 512 16B slots, 2/thread.
        #pragma unroll
        for (int j = 0; j < 2; ++j) {
            const int slot = (j << 8) + tid;          // 0..511 (tid = wave*64+lane)
            const int row  = slot >> 2;               // tile row 0..127
            const int seg  = (slot & 3) << 4;         // 16B segment in 64B row
            const size_t ga = (size_t)(m0 + row) * 1024 + k + seg;
            const size_t gb = (size_t)(n0 + row) * 1024 + k + seg;
            const int lb = ((j << 8) + (wave << 6)) << 4;  // wave-uniform byte base
            async16(A1 + ga, As1 + lb);
            async16(A2 + ga, As2 + lb);
            async16(B1 + gb, Bs1 + lb);
            async16(B2 + gb, Bs2 + lb);
        }
        __syncthreads();                      // vmcnt(0) drain: DMA landed

        intx4 a1[4], b1[4];
        #pragma unroll
        for (int i = 0; i < 4; ++i) {
            a1[i] = *(const intx4*)(As1 + (wm + i * 16 + r) * 64 + q * 16);
            b1[i] = *(const intx4*)(Bs1 + (wn + i * 16 + r) * 64 + q * 16);
        }
        #pragma unroll
        for (int i = 0; i < 4; ++i)
            #pragma unroll
            for (int j = 0; j < 4; ++j)
                accM[i][j] = __builtin_amdgcn_mfma_i32_16x16x64_i8(a1[i], b1[j], accM[i][j], 0, 0, 0);
        intx4 a2[4];
        #pragma unroll
        for (int i = 0; i < 4; ++i)
            a2[i] = *(const intx4*)(As2 + (wm + i * 16 + r) * 64 + q * 16);
        #pragma unroll
        for (int i = 0; i < 4; ++i)
            #pragma unroll
            for (int j = 0; j < 4; ++j)
                accX[i][j] = __builtin_amdgcn_mfma_i32_16x16x64_i8(a2[i], b1[j], accX[i][j], 0, 0, 0);
        intx4 b2[4];
        #pragma unroll
        for (int i = 0; i < 4; ++i)
            b2[i] = *(const intx4*)(Bs2 + (wn + i * 16 + r) * 64 + q * 16);
        #pragma unroll
        for (int i = 0; i < 4; ++i)
            #pragma unroll
            for (int j = 0; j < 4; ++j)
                accX[i][j] = __builtin_amdgcn_mfma_i32_16x16x64_i8(a1[i], b2[j], accX[i][j], 0, 0, 0);
    }

    // Epilogue. C/D layout: col=lane&15, row=(lane>>4)*4+reg.
    #pragma unroll
    for (int j = 0; j < 4; ++j) {
        const int col = n0 + wn + j * 16 + r;
        const float bv = bias[col];
        #pragma unroll
        for (int i = 0; i < 4; ++i) {
            const int row0 = m0 + wm + i * 16 + q * 4;
            #pragma unroll
            for (int rr = 0; rr < 4; ++rr) {
                float pre = fmaf((float)accM[i][j][rr], 0x1p-16f,
                            fmaf((float)accX[i][j][rr], 0x1p-23f, bv));
                float o = tanh_fast(pre);
                signed char q1, q2;
                quant_h(o, q1, q2);
                const size_t idx = (size_t)(row0 + rr) * 1024 + col;
                C1[idx] = q1;
                C2[idx] = q2;
            }
        }
    }
}

// ---------------------------------------------------------------------------
// Final: out[row] = h3[row,:] . W_last + b_last; h3 = H1*2^-6 + H2*2^-13.
// ---------------------------------------------------------------------------
__global__ __launch_bounds__(256)
void final_kernel(const signed char* __restrict__ H1, const signed char* __restrict__ H2,
                  const float* __restrict__ Wl, const float* __restrict__ bl,
                  float* __restrict__ out) {
    const int lane = threadIdx.x & 63;
    const int wave = threadIdx.x >> 6;
    const int row  = blockIdx.x * 4 + wave;
    const size_t base = (size_t)row * 1024;
    float s = 0.0f;
    #pragma unroll
    for (int c = 0; c < 2; ++c) {
        const int e = c * 512 + lane * 8;
        i8x8 h1 = *(const i8x8*)(H1 + base + e);
        i8x8 h2 = *(const i8x8*)(H2 + base + e);
        floatx8 wv = *(const floatx8*)(Wl + e);
        #pragma unroll
        for (int j = 0; j < 8; ++j) {
            float h = fmaf((float)h2[j], 0x1p-13f, (float)h1[j] * 0x1p-6f);
            s = fmaf(h, wv[j], s);
        }
    }
    #pragma unroll
    for (int off = 32; off > 0; off >>= 1) s += __shfl_down(s, off);
    if (lane == 0) out[row] = s + bl[0];
}

// ---------------------------------------------------------------------------
extern "C" void kernel_launch(void* const* d_in, const int* in_sizes, int n_in,
                              void* d_out, int out_size, void* d_ws, size_t ws_size,
                              hipStream_t stream) {
    const float* X  = (const float*)d_in[0];
    const float* W0 = (const float*)d_in[1];
    const float* b0 = (const float*)d_in[2];
    const float* W1 = (const float*)d_in[3];
    const float* b1 = (const float*)d_in[4];
    const float* W2 = (const float*)d_in[5];
    const float* b2 = (const float*)d_in[6];
    const float* W3 = (const float*)d_in[7];
    const float* b3 = (const float*)d_in[8];
    const float* Wl = (const float*)d_in[9];
    const float* bl = (const float*)d_in[10];
    float* out = (float*)d_out;

    const int Nrows = in_sizes[0] / 2;                 // 65536
    const size_t WT = 1024 * 1024;                     // bytes per i8 weight plane
    const size_t wt_bytes = 6 * WT;                    // 6 MiB
    const size_t slack = 512;

    int R = 0;
    const int Rcap = Nrows < 32768 ? Nrows : 32768;
    for (int r = Rcap; r >= 128; r >>= 1)
        if ((size_t)4 * r * 1024 + wt_bytes + slack <= ws_size) { R = r; break; }
    if (!R) return;

    signed char* wsp  = (signed char*)d_ws;
    signed char* Wt1a = wsp;            signed char* Wt1b = Wt1a + WT;
    signed char* Wt2a = Wt1b + WT;      signed char* Wt2b = Wt2a + WT;
    signed char* Wt3a = Wt2b + WT;      signed char* Wt3b = Wt3a + WT;
    const size_t plane = (size_t)R * 1024;
    signed char* P0a = Wt3b + WT;       signed char* P0b = P0a + plane;
    signed char* P1a = P0b + plane;     signed char* P1b = P1a + plane;

    const dim3 tb(256);
    transposeQ<<<dim3(32, 32), tb, 0, stream>>>(W1, Wt1a, Wt1b);
    transposeQ<<<dim3(32, 32), tb, 0, stream>>>(W2, Wt2a, Wt2b);
    transposeQ<<<dim3(32, 32), tb, 0, stream>>>(W3, Wt3a, Wt3b);

    const int nchunks = Nrows / R;
    for (int c = 0; c < nchunks; ++c) {
        const float* Xc = X + (size_t)c * R * 2;
        float* outc = out + (size_t)c * R;

        layer0_kernel<<<R / 2, tb, 0, stream>>>(Xc, W0, b0, P0a, P0b);

        const dim3 gg(8, R / 128);                    // n fast, m slow
        gemm_tanh_i8<<<gg, tb, 0, stream>>>(P0a, P0b, Wt1a, Wt1b, b1, P1a, P1b, 1024);
        gemm_tanh_i8<<<gg, tb, 0, stream>>>(P1a, P1b, Wt2a, Wt2b, b2, P0a, P0b, 512);
        gemm_tanh_i8<<<gg, tb, 0, stream>>>(P0a, P0b, Wt3a, Wt3b, b3, P1a, P1b, 256);

        final_kernel<<<R / 4, tb, 0, stream>>>(P1a, P1b, Wl, bl, outc);
    }
}